// Round 6
// baseline (15772.179 us; speedup 1.0000x reference)
//
#include <hip/hip_runtime.h>
#include <hip/hip_bf16.h>
#include <math.h>

#define NUM_HEADS 16
#define HEAD_DIM  128
#define SEQ       2048
#define DM        2048
#define BATCH     4
#define M_ROWS    (BATCH * SEQ)   // 8192

__device__ inline unsigned short f2bf(float f) {
    union { float f; unsigned u; } x; x.f = f;
    unsigned r = x.u + 0x7FFF + ((x.u >> 16) & 1);   // RNE
    return (unsigned short)(r >> 16);
}

__device__ inline float bf2f(unsigned short u) {
    union { unsigned u; float f; } x; x.u = ((unsigned)u) << 16;
    return x.f;
}

// Simple correctness-first GEMM: C = A(M,K) * B(N,K)^T, fp32 compute.
// A: either f32 row-major (Af) or bf16 [b,h,s,d]-gather (Ag, for final proj).
// B: f32 row-major [N,K] ('nm' indexing -> B[col][k]).
// mode 0: C = Cf, f32 row-major [M,N]  (-> d_out, reference output dtype f32)
// mode 1: C = Cb, bf16 scatter [b,h,s,d]
// mode 2: mode 1 + interleaved RoPE (accurate sincosf).
// Tile 64x64, BK=16, 256 threads, 4x4 micro-tile per thread.
__global__ __launch_bounds__(256)
void sgemm(const float* __restrict__ Af, const unsigned short* __restrict__ Ag,
           const float* __restrict__ B, unsigned short* __restrict__ Cb,
           float* __restrict__ Cf, int mode) {
    __shared__ float As[64][17];
    __shared__ float Bs[64][17];
    const int tid = threadIdx.x;
    const int tx = tid & 15, ty = tid >> 4;
    const int tm = blockIdx.y * 64, tn = blockIdx.x * 64;
    const int lr = tid >> 2;          // 0..63: tile row to load
    const int lc = (tid & 3) * 4;     // 0,4,8,12: k offset to load

    float acc[4][4] = {};

    for (int k0 = 0; k0 < DM; k0 += 16) {
        // stage A
        if (Ag) {
            const int row = tm + lr;
            const int b = row >> 11, s = row & (SEQ - 1);
            const int k = k0 + lc;
            const int h = k >> 7, dd = k & (HEAD_DIM - 1);
            const ushort4 u = *(const ushort4*)&Ag[(((size_t)b * NUM_HEADS + h) * SEQ + s) * HEAD_DIM + dd];
            As[lr][lc + 0] = bf2f(u.x); As[lr][lc + 1] = bf2f(u.y);
            As[lr][lc + 2] = bf2f(u.z); As[lr][lc + 3] = bf2f(u.w);
        } else {
            const float4 v = *(const float4*)&Af[(size_t)(tm + lr) * DM + k0 + lc];
            As[lr][lc + 0] = v.x; As[lr][lc + 1] = v.y;
            As[lr][lc + 2] = v.z; As[lr][lc + 3] = v.w;
        }
        // stage B
        {
            const float4 w = *(const float4*)&B[(size_t)(tn + lr) * DM + k0 + lc];
            Bs[lr][lc + 0] = w.x; Bs[lr][lc + 1] = w.y;
            Bs[lr][lc + 2] = w.z; Bs[lr][lc + 3] = w.w;
        }
        __syncthreads();
        #pragma unroll
        for (int kk = 0; kk < 16; ++kk) {
            float a[4], bb[4];
            #pragma unroll
            for (int i = 0; i < 4; ++i) a[i] = As[ty * 4 + i][kk];
            #pragma unroll
            for (int j = 0; j < 4; ++j) bb[j] = Bs[tx * 4 + j][kk];
            #pragma unroll
            for (int i = 0; i < 4; ++i)
                #pragma unroll
                for (int j = 0; j < 4; ++j)
                    acc[i][j] += a[i] * bb[j];
        }
        __syncthreads();
    }

    // epilogue
    #pragma unroll
    for (int i = 0; i < 4; ++i) {
        const int row = tm + ty * 4 + i;
        float v[4];
        #pragma unroll
        for (int j = 0; j < 4; ++j) v[j] = acc[i][j];
        if (mode == 2) {
            const int s = row & (SEQ - 1);
            #pragma unroll
            for (int jp = 0; jp < 2; ++jp) {
                const int col0 = tn + tx * 4 + jp * 2;       // even col
                const int dcol = col0 & (HEAD_DIM - 1);      // even d index = 2*fi
                const int fi = dcol >> 1;                    // 0..63
                const float ang = (float)s * expf((float)fi * (-9.210340371976184f / 64.f));
                float sn, cs;
                sincosf(ang, &sn, &cs);
                const float e = v[jp * 2], o = v[jp * 2 + 1];
                v[jp * 2]     = e * cs - o * sn;             // rot_even
                v[jp * 2 + 1] = o * cs + e * sn;             // rot_odd
            }
        }
        #pragma unroll
        for (int j = 0; j < 4; ++j) {
            const int col = tn + tx * 4 + j;
            if (mode == 0) {
                Cf[(size_t)row * DM + col] = v[j];           // f32 output
            } else {
                const int b = row >> 11, s = row & (SEQ - 1);
                const int h = col >> 7, dd = col & (HEAD_DIM - 1);
                Cb[(((size_t)b * NUM_HEADS + h) * SEQ + s) * HEAD_DIM + dd] = f2bf(v[j]);
            }
        }
    }
}

// Simple causal attention, one wave per query row, fp32 compute.
// Q,K,V bf16 [b*h, s, d]; Y bf16 same layout (may alias Q: a row is read
// only by its own wave, which reads it before its final write).
// grid (SEQ/4, BATCH*NUM_HEADS), 256 threads (4 waves).
__global__ __launch_bounds__(256)
void sattn(const unsigned short* Q, const unsigned short* __restrict__ K,
           const unsigned short* __restrict__ V, unsigned short* Y) {
    const int tid = threadIdx.x, wave = tid >> 6, lane = tid & 63;
    const int row = blockIdx.x * 4 + wave;
    const int bh = blockIdx.y;
    const size_t base = (size_t)bh * SEQ * HEAD_DIM;
    const int d0 = lane * 2;

    const float q0 = bf2f(Q[base + (size_t)row * HEAD_DIM + d0]);
    const float q1 = bf2f(Q[base + (size_t)row * HEAD_DIM + d0 + 1]);
    const float scale = 0.08838834764831845f;   // 1/sqrt(128)

    float m = -1e30f, l = 0.f, o0 = 0.f, o1 = 0.f;
    for (int kv = 0; kv <= row; ++kv) {
        const float k0 = bf2f(K[base + (size_t)kv * HEAD_DIM + d0]);
        const float k1 = bf2f(K[base + (size_t)kv * HEAD_DIM + d0 + 1]);
        float p = q0 * k0 + q1 * k1;
        p += __shfl_xor(p, 1, 64);  p += __shfl_xor(p, 2, 64);
        p += __shfl_xor(p, 4, 64);  p += __shfl_xor(p, 8, 64);
        p += __shfl_xor(p, 16, 64); p += __shfl_xor(p, 32, 64);
        const float sc = p * scale;
        const float mn = fmaxf(m, sc);
        const float corr = expf(m - mn);
        const float w = expf(sc - mn);
        const float v0 = bf2f(V[base + (size_t)kv * HEAD_DIM + d0]);
        const float v1 = bf2f(V[base + (size_t)kv * HEAD_DIM + d0 + 1]);
        l = l * corr + w;
        o0 = o0 * corr + w * v0;
        o1 = o1 * corr + w * v1;
        m = mn;
    }
    Y[base + (size_t)row * HEAD_DIM + d0]     = f2bf(o0 / l);
    Y[base + (size_t)row * HEAD_DIM + d0 + 1] = f2bf(o1 / l);
}

extern "C" void kernel_launch(void* const* d_in, const int* in_sizes, int n_in,
                              void* d_out, int out_size, void* d_ws, size_t ws_size,
                              hipStream_t stream) {
    // ---- Runtime input identification (robust to ordering surprises) ----
    // Sizes: x = 16,777,216; token_positions = 2048; each W = 4,194,304.
    int xi = -1, pi = -1, wi[4] = {-1, -1, -1, -1};
    int nw = 0;
    for (int i = 0; i < n_in && i < 8; ++i) {
        const long long sz = in_sizes[i];
        if (sz == 16777216) xi = i;
        else if (sz == 2048) pi = i;
        else if (sz == 4194304 && nw < 4) wi[nw++] = i;
    }
    int iq, ik, iv, io;
    if (xi < 0 || nw < 4) {
        xi = 0; iq = 2; ik = 3; iv = 4; io = 5;   // documented dict order
    } else if (pi == 4 && xi == 5) {
        ik = wi[0]; io = wi[1]; iq = wi[2]; iv = wi[3];   // alphabetical
    } else {
        iq = wi[0]; ik = wi[1]; iv = wi[2]; io = wi[3];   // dict order
    }

    const float* x  = (const float*)d_in[xi];
    const float* Wq = (const float*)d_in[iq];
    const float* Wk = (const float*)d_in[ik];
    const float* Wv = (const float*)d_in[iv];
    const float* Wo = (const float*)d_in[io];
    float* out = (float*)d_out;   // reference output dtype is float32

    // ws (ushorts): [Qb | Kb | Vb], 32 MiB each = 96 MiB. Y aliases Qb.
    unsigned short* ws16 = (unsigned short*)d_ws;
    unsigned short* Qb = ws16;
    unsigned short* Kb = Qb + (1ull << 24);
    unsigned short* Vb = Kb + (1ull << 24);

    dim3 blk(256);
    dim3 gg(DM / 64, M_ROWS / 64);   // (32, 128)

    sgemm<<<gg, blk, 0, stream>>>(x, nullptr, Wq, Qb, nullptr, 2);   // Q + RoPE
    sgemm<<<gg, blk, 0, stream>>>(x, nullptr, Wk, Kb, nullptr, 2);   // K + RoPE
    sgemm<<<gg, blk, 0, stream>>>(x, nullptr, Wv, Vb, nullptr, 1);   // V
    sattn<<<dim3(SEQ / 4, BATCH * NUM_HEADS), blk, 0, stream>>>(Qb, Kb, Vb, Qb);
    sgemm<<<gg, blk, 0, stream>>>(nullptr, Qb, Wo, nullptr, out, 0); // out proj (f32)
}